// Round 1
// baseline (1692.962 us; speedup 1.0000x reference)
//
#include <hip/hip_runtime.h>
#include <math.h>

#define B_    4
#define N_    200000
#define E_    128
#define IDX_  2048
#define TT    (B_*N_)
#define INV_NORM 0.08838834764831845f   /* 1/sqrt(128) */
#define CAP   1024

__device__ __forceinline__ float fast_tanh(float v) {
    float a = fabsf(v);
    float t = __expf(-2.f * a);
    float r = (1.f - t) / (1.f + t);
    return v < 0.f ? -r : r;
}

/* ---------------- Kernel A: scores = mask ? ctx.tanh(Wx+b)/sqrt(E) : -1e9 --------------- */
__global__ __launch_bounds__(256) void score_kernel(
    const float* __restrict__ x, const float* __restrict__ W,
    const float* __restrict__ bias, const float* __restrict__ ctx,
    const int* __restrict__ mask, float* __restrict__ scores)
{
    __shared__ float Wl[E_][132];     /* pad 132: wave b128 reads hit all 32 banks */
    __shared__ float xl[16][E_];
    __shared__ float red[2][8][2];

    const int tid = threadIdx.x;
    const int f   = tid & 127;        /* output feature this thread owns */
    const int g   = tid >> 7;         /* token group 0/1 (8 tokens each) */

    for (int i = tid; i < E_ * 32; i += 256) {
        int fr = i >> 5, ec = i & 31;
        float4 v = ((const float4*)W)[i];
        *(float4*)&Wl[fr][ec * 4] = v;
    }
    float bf = bias[f], cf = ctx[f];
    __syncthreads();

    for (long chunk = (long)blockIdx.x * 16; chunk < TT; chunk += (long)gridDim.x * 16) {
        /* cooperative load of 16 token rows */
        for (int i = tid; i < 16 * 32; i += 256) {
            int t = i >> 5, ec = i & 31;
            ((float4*)&xl[t][0])[ec] = ((const float4*)(x + (chunk + t) * (long)E_))[ec];
        }
        __syncthreads();

        float h[8];
#pragma unroll
        for (int t = 0; t < 8; t++) h[t] = 0.f;

#pragma unroll 4
        for (int ec = 0; ec < 32; ec++) {
            float4 wv = *(const float4*)&Wl[f][ec * 4];
#pragma unroll
            for (int t = 0; t < 8; t++) {
                float4 xv = *(const float4*)&xl[g * 8 + t][ec * 4];  /* wave-broadcast */
                h[t] = fmaf(wv.x, xv.x, h[t]);
                h[t] = fmaf(wv.y, xv.y, h[t]);
                h[t] = fmaf(wv.z, xv.z, h[t]);
                h[t] = fmaf(wv.w, xv.w, h[t]);
            }
        }

#pragma unroll
        for (int t = 0; t < 8; t++) {
            float v = fast_tanh(h[t] + bf) * cf;
#pragma unroll
            for (int off = 32; off > 0; off >>= 1) v += __shfl_down(v, off, 64);
            if ((tid & 63) == 0) red[g][t][(tid >> 6) & 1] = v;
        }
        __syncthreads();

        if (tid < 16) {
            long tok = chunk + tid;
            float s = (red[tid >> 3][tid & 7][0] + red[tid >> 3][tid & 7][1]) * INV_NORM;
            if (mask[tok] == 0) s = -1e9f;
            scores[tok] = s;
        }
        __syncthreads();   /* protect red & xl for next iteration */
    }
}

/* ---------------- Kernel B: histogram of (b, index) --------------- */
__global__ void hist_kernel(const int* __restrict__ index, int* __restrict__ counts)
{
    for (int tok = blockIdx.x * blockDim.x + threadIdx.x; tok < TT;
         tok += gridDim.x * blockDim.x) {
        int b = tok / N_;
        atomicAdd(&counts[b * IDX_ + index[tok]], 1);
    }
}

/* ---------------- Kernel C: exclusive scan over 8192 counters --------------- */
__global__ __launch_bounds__(1024) void scan_kernel(
    const int* __restrict__ counts, int* __restrict__ offsets, int* __restrict__ cursor)
{
    __shared__ int sums[1024];
    int tid = threadIdx.x;
    int c[8], loc[8], s = 0;
#pragma unroll
    for (int j = 0; j < 8; j++) { c[j] = counts[tid * 8 + j]; loc[j] = s; s += c[j]; }
    sums[tid] = s;
    __syncthreads();
    for (int off = 1; off < 1024; off <<= 1) {
        int v = (tid >= off) ? sums[tid - off] : 0;
        __syncthreads();
        if (tid >= off) sums[tid] += v;
        __syncthreads();
    }
    int base = (tid > 0) ? sums[tid - 1] : 0;
#pragma unroll
    for (int j = 0; j < 8; j++) {
        int o = base + loc[j];
        offsets[tid * 8 + j] = o;
        cursor[tid * 8 + j]  = o;
    }
}

/* ---------------- Kernel D: scatter token ids into segment lists --------------- */
__global__ void scatter_kernel(const int* __restrict__ index, int* __restrict__ cursor,
                               int* __restrict__ tokenlist)
{
    for (int tok = blockIdx.x * blockDim.x + threadIdx.x; tok < TT;
         tok += gridDim.x * blockDim.x) {
        int b = tok / N_;
        int pos = atomicAdd(&cursor[b * IDX_ + index[tok]], 1);
        tokenlist[pos] = tok;
    }
}

/* ---------------- Kernel E: per-(b,seg) softmax + weighted sum --------------- */
__global__ __launch_bounds__(128) void attend_kernel(
    const float* __restrict__ x, const int* __restrict__ counts,
    const int* __restrict__ offsets, const int* __restrict__ tokenlist,
    float* __restrict__ attn /* in: scores, out: weights */, float* __restrict__ out)
{
    const int key = blockIdx.x;      /* b*IDX + seg */
    const int e   = threadIdx.x;     /* 0..127 */
    const int cnt = counts[key];
    const int off = offsets[key];

    if (cnt == 0) { out[(size_t)key * E_ + e] = 0.f; return; }

    __shared__ int   toks[CAP];
    __shared__ float wv[CAP];
    __shared__ float rbuf[2];

    /* phase 1: load list, compute max */
    float m = -INFINITY;
    for (int j = e; j < cnt; j += 128) {
        int t = tokenlist[off + j];
        float s = attn[t];
        if (j < CAP) { toks[j] = t; wv[j] = s; }
        m = fmaxf(m, s);
    }
#pragma unroll
    for (int o = 32; o > 0; o >>= 1) m = fmaxf(m, __shfl_xor(m, o, 64));
    if ((e & 63) == 0) rbuf[e >> 6] = m;
    __syncthreads();
    m = fmaxf(rbuf[0], rbuf[1]);
    __syncthreads();

    /* phase 2: sum of exp */
    float sum = 0.f;
    for (int j = e; j < cnt; j += 128) {
        float s = (j < CAP) ? wv[j] : attn[tokenlist[off + j]];
        float ev = __expf(s - m);
        if (j < CAP) wv[j] = ev;
        sum += ev;
    }
#pragma unroll
    for (int o = 32; o > 0; o >>= 1) sum += __shfl_xor(sum, o, 64);
    if ((e & 63) == 0) rbuf[e >> 6] = sum;
    __syncthreads();
    float inv = 1.f / (rbuf[0] + rbuf[1]);

    /* write attention weights */
    for (int j = e; j < cnt; j += 128) {
        int t; float ev;
        if (j < CAP) { t = toks[j]; ev = wv[j]; }
        else         { t = tokenlist[off + j]; ev = __expf(attn[t] - m); }
        float w = ev * inv;
        if (j < CAP) wv[j] = w;
        attn[t] = w;
    }
    __syncthreads();

    /* phase 3: out[key,:] = sum_j w_j * x[t_j,:]  (thread e owns dim e) */
    float acc = 0.f;
    for (int j = 0; j < cnt; j++) {
        int t; float w;
        if (j < CAP) { t = toks[j]; w = wv[j]; }
        else         { t = tokenlist[off + j]; w = attn[t]; }
        acc = fmaf(w, x[(size_t)t * E_ + e], acc);
    }
    out[(size_t)key * E_ + e] = acc;
}

extern "C" void kernel_launch(void* const* d_in, const int* in_sizes, int n_in,
                              void* d_out, int out_size, void* d_ws, size_t ws_size,
                              hipStream_t stream)
{
    const float* x    = (const float*)d_in[0];
    const float* W    = (const float*)d_in[1];
    const float* bias = (const float*)d_in[2];
    const float* ctx  = (const float*)d_in[3];
    const int*   mask = (const int*)d_in[4];
    const int*   index= (const int*)d_in[5];

    float* out  = (float*)d_out;                         /* B*IDX*E */
    float* attn = out + (size_t)B_ * IDX_ * E_;          /* B*N: scores then weights */

    int* counts    = (int*)d_ws;
    int* offsets   = counts  + B_ * IDX_;
    int* cursor    = offsets + B_ * IDX_;
    int* tokenlist = cursor  + B_ * IDX_;

    hipMemsetAsync(counts, 0, B_ * IDX_ * sizeof(int), stream);
    score_kernel  <<<512, 256, 0, stream>>>(x, W, bias, ctx, mask, attn);
    hist_kernel   <<<512, 256, 0, stream>>>(index, counts);
    scan_kernel   <<<1, 1024, 0, stream>>>(counts, offsets, cursor);
    scatter_kernel<<<512, 256, 0, stream>>>(index, cursor, tokenlist);
    attend_kernel <<<B_ * IDX_, 128, 0, stream>>>(x, counts, offsets, tokenlist, attn, out);
}

// Round 2
// 805.938 us; speedup vs baseline: 2.1006x; 2.1006x over previous
//
#include <hip/hip_runtime.h>
#include <math.h>

#define B_    4
#define N_    200000
#define E_    128
#define IDX_  2048
#define TT    (B_*N_)
#define INV_NORM 0.08838834764831845f   /* 1/sqrt(128) */
#define CAP   512
#define WPAD  136                       /* bf16 elems per W row in LDS: 272B -> 2-way bank alias (free) */

typedef __attribute__((ext_vector_type(8))) short bf16x8;
typedef __attribute__((ext_vector_type(4))) float f32x4;

__device__ __forceinline__ float fast_tanh(float v) {
    float a = fabsf(v);
    float t = __expf(-2.f * a);
    float r = (1.f - t) / (1.f + t);
    return v < 0.f ? -r : r;
}

__device__ __forceinline__ unsigned short f2bf(float f) {
    unsigned int u = __float_as_uint(f);
    unsigned int r = (u + 0x7fffu + ((u >> 16) & 1u)) >> 16;
    return (unsigned short)r;
}

/* ---- Kernel A: scores via bf16 MFMA: s = mask ? ctx.tanh(x@W^T+b)/sqrt(E) : -1e9 ---- */
__global__ __launch_bounds__(256) void score_kernel(
    const float* __restrict__ x, const float* __restrict__ W,
    const float* __restrict__ bias, const float* __restrict__ ctx,
    const int* __restrict__ mask, float* __restrict__ scores)
{
    __shared__ unsigned short Wb[E_ * WPAD];   /* 34816 B */

    const int tid = threadIdx.x;

    /* stage W: fp32 global -> bf16 LDS (once per block) */
    for (int i = tid; i < E_ * E_ / 4; i += 256) {
        int f = i >> 5, kb = (i & 31) * 4;
        float4 v = ((const float4*)W)[i];
        ushort4 o;
        o.x = f2bf(v.x); o.y = f2bf(v.y); o.z = f2bf(v.z); o.w = f2bf(v.w);
        *(ushort4*)&Wb[f * WPAD + kb] = o;
    }
    __syncthreads();

    const int lane = tid & 63;
    const int col  = lane & 15;      /* feature-within-ntile / token-within-mtile */
    const int q    = lane >> 4;      /* quad: k-subrange for A/B, row-group for C */
    const int wave = tid >> 6;

    /* per-lane ctx/bias for features n*16+col */
    float ctx_r[8], bias_r[8];
#pragma unroll
    for (int n = 0; n < 8; n++) { ctx_r[n] = ctx[n * 16 + col]; bias_r[n] = bias[n * 16 + col]; }

    /* persistent B fragments: Bf[n][kt] = W[n*16+col][kt*32+q*8 .. +7] */
    bf16x8 Bf[8][4];
#pragma unroll
    for (int n = 0; n < 8; n++)
#pragma unroll
        for (int kt = 0; kt < 4; kt++)
            Bf[n][kt] = *(const bf16x8*)&Wb[(n * 16 + col) * WPAD + kt * 32 + q * 8];

    for (long base0 = (long)blockIdx.x * 64; base0 < TT; base0 += (long)gridDim.x * 64) {
        const long tbase = base0 + wave * 16;
        const float* xrow = x + (tbase + col) * (long)E_;

        /* A fragments: Af[kt] = x[tbase+col][kt*32+q*8 .. +7], fp32->bf16 */
        bf16x8 Af[4];
#pragma unroll
        for (int kt = 0; kt < 4; kt++) {
            float4 u = ((const float4*)xrow)[kt * 8 + q * 2];
            float4 v = ((const float4*)xrow)[kt * 8 + q * 2 + 1];
            bf16x8 a;
            a[0] = (short)f2bf(u.x); a[1] = (short)f2bf(u.y);
            a[2] = (short)f2bf(u.z); a[3] = (short)f2bf(u.w);
            a[4] = (short)f2bf(v.x); a[5] = (short)f2bf(v.y);
            a[6] = (short)f2bf(v.z); a[7] = (short)f2bf(v.w);
            Af[kt] = a;
        }

        f32x4 acc[8];
#pragma unroll
        for (int n = 0; n < 8; n++) acc[n] = (f32x4){0.f, 0.f, 0.f, 0.f};

#pragma unroll
        for (int kt = 0; kt < 4; kt++)
#pragma unroll
            for (int n = 0; n < 8; n++)
                acc[n] = __builtin_amdgcn_mfma_f32_16x16x32_bf16(Af[kt], Bf[n][kt], acc[n], 0, 0, 0);

        /* epilogue: p[r] = sum_n ctx*tanh(acc+bias); token = tbase + q*4 + r */
        float pr[4];
#pragma unroll
        for (int r = 0; r < 4; r++) {
            float p = 0.f;
#pragma unroll
            for (int n = 0; n < 8; n++) p = fmaf(ctx_r[n], fast_tanh(acc[n][r] + bias_r[n]), p);
#pragma unroll
            for (int o = 1; o < 16; o <<= 1) p += __shfl_xor(p, o);
            pr[r] = p * INV_NORM;
        }
        if (col == 0) {
            int4 mv = ((const int4*)(mask + tbase))[q];
            float4 s;
            s.x = mv.x ? pr[0] : -1e9f;
            s.y = mv.y ? pr[1] : -1e9f;
            s.z = mv.z ? pr[2] : -1e9f;
            s.w = mv.w ? pr[3] : -1e9f;
            ((float4*)(scores + tbase))[q] = s;
        }
    }
}

/* ---------------- Kernel B: histogram of (b, index) --------------- */
__global__ void hist_kernel(const int* __restrict__ index, int* __restrict__ counts)
{
    for (int tok = blockIdx.x * blockDim.x + threadIdx.x; tok < TT;
         tok += gridDim.x * blockDim.x) {
        int b = tok / N_;
        atomicAdd(&counts[b * IDX_ + index[tok]], 1);
    }
}

/* ---------------- Kernel C: exclusive scan over 8192 counters --------------- */
__global__ __launch_bounds__(1024) void scan_kernel(
    const int* __restrict__ counts, int* __restrict__ offsets, int* __restrict__ cursor)
{
    __shared__ int sums[1024];
    int tid = threadIdx.x;
    int c[8], loc[8], s = 0;
#pragma unroll
    for (int j = 0; j < 8; j++) { c[j] = counts[tid * 8 + j]; loc[j] = s; s += c[j]; }
    sums[tid] = s;
    __syncthreads();
    for (int off = 1; off < 1024; off <<= 1) {
        int v = (tid >= off) ? sums[tid - off] : 0;
        __syncthreads();
        if (tid >= off) sums[tid] += v;
        __syncthreads();
    }
    int base = (tid > 0) ? sums[tid - 1] : 0;
#pragma unroll
    for (int j = 0; j < 8; j++) {
        int o = base + loc[j];
        offsets[tid * 8 + j] = o;
        cursor[tid * 8 + j]  = o;
    }
}

/* ---------------- Kernel D: scatter token ids into segment lists --------------- */
__global__ void scatter_kernel(const int* __restrict__ index, int* __restrict__ cursor,
                               int* __restrict__ tokenlist)
{
    for (int tok = blockIdx.x * blockDim.x + threadIdx.x; tok < TT;
         tok += gridDim.x * blockDim.x) {
        int b = tok / N_;
        int pos = atomicAdd(&cursor[b * IDX_ + index[tok]], 1);
        tokenlist[pos] = tok;
    }
}

/* ---------------- Kernel E: per-(b,seg) softmax + weighted sum --------------- */
__global__ __launch_bounds__(128) void attend_kernel(
    const float* __restrict__ x, const int* __restrict__ counts,
    const int* __restrict__ offsets, const int* __restrict__ tokenlist,
    float* __restrict__ attn /* in: scores, out: weights */, float* __restrict__ out)
{
    const int key = blockIdx.x;      /* b*IDX + seg */
    const int e   = threadIdx.x;     /* 0..127 */
    const int cnt = counts[key];
    const int off = offsets[key];

    if (cnt == 0) { out[(size_t)key * E_ + e] = 0.f; return; }

    __shared__ int   toks[CAP];
    __shared__ float wv[CAP];
    __shared__ float rbuf[2];

    if (cnt <= CAP) {
        /* ---- fast path: whole list fits in LDS ---- */
        float m = -INFINITY;
        for (int j = e; j < cnt; j += 128) {
            int t = tokenlist[off + j];
            float s = attn[t];
            toks[j] = t; wv[j] = s;
            m = fmaxf(m, s);
        }
#pragma unroll
        for (int o = 32; o > 0; o >>= 1) m = fmaxf(m, __shfl_xor(m, o));
        if ((e & 63) == 0) rbuf[e >> 6] = m;
        __syncthreads();
        m = fmaxf(rbuf[0], rbuf[1]);
        __syncthreads();

        float sum = 0.f;
        for (int j = e; j < cnt; j += 128) {
            float ev = __expf(wv[j] - m);
            wv[j] = ev;
            sum += ev;
        }
#pragma unroll
        for (int o = 32; o > 0; o >>= 1) sum += __shfl_xor(sum, o);
        if ((e & 63) == 0) rbuf[e >> 6] = sum;
        __syncthreads();
        float inv = 1.f / (rbuf[0] + rbuf[1]);

        for (int j = e; j < cnt; j += 128) {
            float w = wv[j] * inv;
            wv[j] = w;
            attn[toks[j]] = w;
        }
        __syncthreads();

        /* weighted sum, unrolled x4 for MLP */
        float acc = 0.f;
        int j = 0;
        for (; j + 4 <= cnt; j += 4) {
            int t0 = toks[j], t1 = toks[j+1], t2 = toks[j+2], t3 = toks[j+3];
            float w0 = wv[j], w1 = wv[j+1], w2 = wv[j+2], w3 = wv[j+3];
            float x0 = x[(size_t)t0 * E_ + e];
            float x1 = x[(size_t)t1 * E_ + e];
            float x2 = x[(size_t)t2 * E_ + e];
            float x3 = x[(size_t)t3 * E_ + e];
            acc = fmaf(w0, x0, acc);
            acc = fmaf(w1, x1, acc);
            acc = fmaf(w2, x2, acc);
            acc = fmaf(w3, x3, acc);
        }
        for (; j < cnt; j++) acc = fmaf(wv[j], x[(size_t)toks[j] * E_ + e], acc);
        out[(size_t)key * E_ + e] = acc;
    } else {
        /* ---- slow path (cnt > CAP): all from global ---- */
        float m = -INFINITY;
        for (int j = e; j < cnt; j += 128) m = fmaxf(m, attn[tokenlist[off + j]]);
#pragma unroll
        for (int o = 32; o > 0; o >>= 1) m = fmaxf(m, __shfl_xor(m, o));
        if ((e & 63) == 0) rbuf[e >> 6] = m;
        __syncthreads();
        m = fmaxf(rbuf[0], rbuf[1]);
        __syncthreads();

        float sum = 0.f;
        for (int j = e; j < cnt; j += 128) sum += __expf(attn[tokenlist[off + j]] - m);
#pragma unroll
        for (int o = 32; o > 0; o >>= 1) sum += __shfl_xor(sum, o);
        if ((e & 63) == 0) rbuf[e >> 6] = sum;
        __syncthreads();
        float inv = 1.f / (rbuf[0] + rbuf[1]);
        __syncthreads();

        for (int j = e; j < cnt; j += 128) {
            int t = tokenlist[off + j];
            attn[t] = __expf(attn[t] - m) * inv;   /* safe: each token touched once */
        }
        /* need all weights written before phase 3 reads them */
        __threadfence();
        __syncthreads();

        float acc = 0.f;
        for (int j = 0; j < cnt; j++) {
            int t = tokenlist[off + j];
            acc = fmaf(attn[t], x[(size_t)t * E_ + e], acc);
        }
        out[(size_t)key * E_ + e] = acc;
    }
}

extern "C" void kernel_launch(void* const* d_in, const int* in_sizes, int n_in,
                              void* d_out, int out_size, void* d_ws, size_t ws_size,
                              hipStream_t stream)
{
    const float* x    = (const float*)d_in[0];
    const float* W    = (const float*)d_in[1];
    const float* bias = (const float*)d_in[2];
    const float* ctx  = (const float*)d_in[3];
    const int*   mask = (const int*)d_in[4];
    const int*   index= (const int*)d_in[5];

    float* out  = (float*)d_out;                         /* B*IDX*E */
    float* attn = out + (size_t)B_ * IDX_ * E_;          /* B*N: scores then weights */

    int* counts    = (int*)d_ws;
    int* offsets   = counts  + B_ * IDX_;
    int* cursor    = offsets + B_ * IDX_;
    int* tokenlist = cursor  + B_ * IDX_;

    hipMemsetAsync(counts, 0, B_ * IDX_ * sizeof(int), stream);
    score_kernel  <<<2048, 256, 0, stream>>>(x, W, bias, ctx, mask, attn);
    hist_kernel   <<<512, 256, 0, stream>>>(index, counts);
    scan_kernel   <<<1, 1024, 0, stream>>>(counts, offsets, cursor);
    scatter_kernel<<<512, 256, 0, stream>>>(index, cursor, tokenlist);
    attend_kernel <<<B_ * IDX_, 128, 0, stream>>>(x, counts, offsets, tokenlist, attn, out);
}

// Round 3
// 739.147 us; speedup vs baseline: 2.2904x; 1.0904x over previous
//
#include <hip/hip_runtime.h>
#include <hip/hip_bf16.h>
#include <math.h>

#define B_    4
#define N_    200000
#define E_    128
#define IDX_  2048
#define TT    (B_*N_)
#define INV_NORM 0.08838834764831845f   /* 1/sqrt(128) */
#define CAP   512
#define WPAD  136                       /* bf16 elems per W row in LDS */

typedef __attribute__((ext_vector_type(8))) short bf16x8;
typedef __attribute__((ext_vector_type(4))) float f32x4;

__device__ __forceinline__ unsigned short f2bf(float f) {
    unsigned int u = __float_as_uint(f);
    unsigned int r = (u + 0x7fffu + ((u >> 16) & 1u)) >> 16;
    return (unsigned short)r;
}

/* ---- Kernel A: scores via bf16 MFMA + fused histogram ----
 * s = mask ? ctx.tanh(x@W^T+b)/sqrt(E) : -1e9 ;  counts[b,idx]++
 * epilogue identity: ctx.tanh(v) = sum(ctx) - 2*sum(ctx/(1+e^{2v})) */
__global__ __launch_bounds__(256) void score_kernel(
    const float* __restrict__ x, const float* __restrict__ W,
    const float* __restrict__ bias, const float* __restrict__ ctx,
    const int* __restrict__ mask, const int* __restrict__ index,
    float* __restrict__ scores, int* __restrict__ counts)
{
    __shared__ unsigned short Wb[E_ * WPAD];   /* 34816 B */

    const int tid = threadIdx.x;

    /* stage W: fp32 global -> bf16 LDS (once per block) */
    for (int i = tid; i < E_ * E_ / 4; i += 256) {
        int f = i >> 5, kb = (i & 31) * 4;
        float4 v = ((const float4*)W)[i];
        ushort4 o;
        o.x = f2bf(v.x); o.y = f2bf(v.y); o.z = f2bf(v.z); o.w = f2bf(v.w);
        *(ushort4*)&Wb[f * WPAD + kb] = o;
    }
    __syncthreads();

    const int lane = tid & 63;
    const int col  = lane & 15;      /* feature-within-ntile / token-within-mtile */
    const int q    = lane >> 4;      /* quad: k-subrange for A/B, row-group for C */
    const int wave = tid >> 6;

    /* per-lane ctx / 2*bias for features n*16+col; csum = sum of this lane's ctx */
    float ctx_r[8], bias2[8], csum = 0.f;
#pragma unroll
    for (int n = 0; n < 8; n++) {
        ctx_r[n] = ctx[n * 16 + col];
        bias2[n] = 2.f * bias[n * 16 + col];
        csum += ctx_r[n];
    }
    const float csum_n = csum * INV_NORM;

    /* persistent B fragments: Bf[n][kt] = W[n*16+col][kt*32+q*8 .. +7] */
    bf16x8 Bf[8][4];
#pragma unroll
    for (int n = 0; n < 8; n++)
#pragma unroll
        for (int kt = 0; kt < 4; kt++)
            Bf[n][kt] = *(const bf16x8*)&Wb[(n * 16 + col) * WPAD + kt * 32 + q * 8];

    for (long base0 = (long)blockIdx.x * 64; base0 < TT; base0 += (long)gridDim.x * 64) {
        const long tbase = base0 + wave * 16;
        const float* xrow = x + (tbase + col) * (long)E_;

        /* A fragments: Af[kt] = x[tbase+col][kt*32+q*8 .. +7], fp32->bf16 packed */
        bf16x8 Af[4];
#pragma unroll
        for (int kt = 0; kt < 4; kt++) {
            float4 u = ((const float4*)xrow)[kt * 8 + q * 2];
            float4 v = ((const float4*)xrow)[kt * 8 + q * 2 + 1];
            union { bf16x8 vec; __hip_bfloat162 h[4]; } a;
            a.h[0] = __float22bfloat162_rn(make_float2(u.x, u.y));
            a.h[1] = __float22bfloat162_rn(make_float2(u.z, u.w));
            a.h[2] = __float22bfloat162_rn(make_float2(v.x, v.y));
            a.h[3] = __float22bfloat162_rn(make_float2(v.z, v.w));
            Af[kt] = a.vec;
        }

        f32x4 acc[8];
#pragma unroll
        for (int n = 0; n < 8; n++) acc[n] = (f32x4){0.f, 0.f, 0.f, 0.f};

#pragma unroll
        for (int kt = 0; kt < 4; kt++)
#pragma unroll
            for (int n = 0; n < 8; n++)
                acc[n] = __builtin_amdgcn_mfma_f32_16x16x32_bf16(Af[kt], Bf[n][kt], acc[n], 0, 0, 0);

        /* epilogue: p_r = csum_n - 2*INV_NORM * sum_n ctx_n/(1+e^{2(acc+bias)}) */
        float pr[4];
#pragma unroll
        for (int r = 0; r < 4; r++) {
            float psum = 0.f;
#pragma unroll
            for (int n = 0; n < 8; n++) {
                float t = fmaf(acc[n][r], 2.f, bias2[n]);
                float rc = __builtin_amdgcn_rcpf(1.f + __expf(t));
                psum = fmaf(ctx_r[n], rc, psum);
            }
            float p = fmaf(-2.f * INV_NORM, psum, csum_n);
#pragma unroll
            for (int o = 1; o < 16; o <<= 1) p += __shfl_xor(p, o);
            pr[r] = p;
        }
        if (col == 0) {
            int4 mv = ((const int4*)(mask + tbase))[q];
            float4 s;
            s.x = mv.x ? pr[0] : -1e9f;
            s.y = mv.y ? pr[1] : -1e9f;
            s.z = mv.z ? pr[2] : -1e9f;
            s.w = mv.w ? pr[3] : -1e9f;
            ((float4*)(scores + tbase))[q] = s;

            /* fused histogram (all tokens, mask-independent) */
            int4 iv = ((const int4*)(index + tbase))[q];
            int* cb = counts + (int)(tbase / N_) * IDX_;
            atomicAdd(&cb[iv.x], 1);
            atomicAdd(&cb[iv.y], 1);
            atomicAdd(&cb[iv.z], 1);
            atomicAdd(&cb[iv.w], 1);
        }
    }
}

/* ---------------- Kernel C: exclusive scan over 8192 counters --------------- */
__global__ __launch_bounds__(1024) void scan_kernel(
    const int* __restrict__ counts, int* __restrict__ offsets, int* __restrict__ cursor)
{
    __shared__ int sums[1024];
    int tid = threadIdx.x;
    int c[8], loc[8], s = 0;
#pragma unroll
    for (int j = 0; j < 8; j++) { c[j] = counts[tid * 8 + j]; loc[j] = s; s += c[j]; }
    sums[tid] = s;
    __syncthreads();
    for (int off = 1; off < 1024; off <<= 1) {
        int v = (tid >= off) ? sums[tid - off] : 0;
        __syncthreads();
        if (tid >= off) sums[tid] += v;
        __syncthreads();
    }
    int base = (tid > 0) ? sums[tid - 1] : 0;
#pragma unroll
    for (int j = 0; j < 8; j++) {
        int o = base + loc[j];
        offsets[tid * 8 + j] = o;
        cursor[tid * 8 + j]  = o;
    }
}

/* ---------------- Kernel D: scatter token ids into segment lists --------------- */
__global__ void scatter_kernel(const int* __restrict__ index, int* __restrict__ cursor,
                               int* __restrict__ tokenlist)
{
    for (int tok = blockIdx.x * blockDim.x + threadIdx.x; tok < TT;
         tok += gridDim.x * blockDim.x) {
        int b = tok / N_;
        int pos = atomicAdd(&cursor[b * IDX_ + index[tok]], 1);
        tokenlist[pos] = tok;
    }
}

/* ------- Kernel E: per-(b,seg) softmax + weighted sum; 256 thr = 2 j-slices x 128 dims ------- */
__global__ __launch_bounds__(256) void attend_kernel(
    const float* __restrict__ x, const int* __restrict__ counts,
    const int* __restrict__ offsets, const int* __restrict__ tokenlist,
    float* __restrict__ attn /* in: scores, out: weights */, float* __restrict__ out)
{
    const int key   = blockIdx.x;      /* b*IDX + seg */
    const int tid   = threadIdx.x;
    const int e     = tid & 127;       /* dim */
    const int slice = tid >> 7;        /* j-slice 0/1 */
    const int cnt   = counts[key];
    const int off   = offsets[key];

    if (cnt == 0) { if (slice == 0) out[(size_t)key * E_ + e] = 0.f; return; }

    __shared__ int   toks[CAP];
    __shared__ float wv[CAP];
    __shared__ float rbuf[4];
    __shared__ float part[E_];

    if (cnt <= CAP) {
        /* ---- fast path: whole list in LDS ---- */
        float m = -INFINITY;
        for (int j = tid; j < cnt; j += 256) {
            int t = tokenlist[off + j];
            float s = attn[t];
            toks[j] = t; wv[j] = s;
            m = fmaxf(m, s);
        }
#pragma unroll
        for (int o = 32; o > 0; o >>= 1) m = fmaxf(m, __shfl_xor(m, o));
        if ((tid & 63) == 0) rbuf[tid >> 6] = m;
        __syncthreads();
        m = fmaxf(fmaxf(rbuf[0], rbuf[1]), fmaxf(rbuf[2], rbuf[3]));
        __syncthreads();

        float sum = 0.f;
        for (int j = tid; j < cnt; j += 256) {
            float ev = __expf(wv[j] - m);
            wv[j] = ev;
            sum += ev;
        }
#pragma unroll
        for (int o = 32; o > 0; o >>= 1) sum += __shfl_xor(sum, o);
        if ((tid & 63) == 0) rbuf[tid >> 6] = sum;
        __syncthreads();
        float inv = 1.f / (rbuf[0] + rbuf[1] + rbuf[2] + rbuf[3]);

        for (int j = tid; j < cnt; j += 256) {
            float w = wv[j] * inv;
            wv[j] = w;
            attn[toks[j]] = w;
        }
        __syncthreads();

        /* weighted sum: slice s takes j ≡ s (mod 2), unrolled x4 */
        float acc = 0.f;
        int j = slice;
        for (; j + 6 < cnt; j += 8) {
            int   t0 = toks[j],   t1 = toks[j+2], t2 = toks[j+4], t3 = toks[j+6];
            float w0 = wv[j],     w1 = wv[j+2],   w2 = wv[j+4],   w3 = wv[j+6];
            float x0 = x[(size_t)t0 * E_ + e];
            float x1 = x[(size_t)t1 * E_ + e];
            float x2 = x[(size_t)t2 * E_ + e];
            float x3 = x[(size_t)t3 * E_ + e];
            acc = fmaf(w0, x0, acc);
            acc = fmaf(w1, x1, acc);
            acc = fmaf(w2, x2, acc);
            acc = fmaf(w3, x3, acc);
        }
        for (; j < cnt; j += 2) acc = fmaf(wv[j], x[(size_t)toks[j] * E_ + e], acc);

        if (slice == 1) part[e] = acc;
        __syncthreads();
        if (slice == 0) out[(size_t)key * E_ + e] = acc + part[e];
    } else {
        /* ---- slow path (cnt > CAP): never taken at these sizes, kept for safety ---- */
        float m = -INFINITY;
        for (int j = tid; j < cnt; j += 256) m = fmaxf(m, attn[tokenlist[off + j]]);
#pragma unroll
        for (int o = 32; o > 0; o >>= 1) m = fmaxf(m, __shfl_xor(m, o));
        if ((tid & 63) == 0) rbuf[tid >> 6] = m;
        __syncthreads();
        m = fmaxf(fmaxf(rbuf[0], rbuf[1]), fmaxf(rbuf[2], rbuf[3]));
        __syncthreads();

        float sum = 0.f;
        for (int j = tid; j < cnt; j += 256) sum += __expf(attn[tokenlist[off + j]] - m);
#pragma unroll
        for (int o = 32; o > 0; o >>= 1) sum += __shfl_xor(sum, o);
        if ((tid & 63) == 0) rbuf[tid >> 6] = sum;
        __syncthreads();
        float inv = 1.f / (rbuf[0] + rbuf[1] + rbuf[2] + rbuf[3]);
        __syncthreads();

        for (int j = tid; j < cnt; j += 256) {
            int t = tokenlist[off + j];
            attn[t] = __expf(attn[t] - m) * inv;
        }
        __threadfence();
        __syncthreads();

        float acc = 0.f;
        for (int j = slice; j < cnt; j += 2) {
            int t = tokenlist[off + j];
            acc = fmaf(attn[t], x[(size_t)t * E_ + e], acc);
        }
        if (slice == 1) part[e] = acc;
        __syncthreads();
        if (slice == 0) out[(size_t)key * E_ + e] = acc + part[e];
    }
}

extern "C" void kernel_launch(void* const* d_in, const int* in_sizes, int n_in,
                              void* d_out, int out_size, void* d_ws, size_t ws_size,
                              hipStream_t stream)
{
    const float* x    = (const float*)d_in[0];
    const float* W    = (const float*)d_in[1];
    const float* bias = (const float*)d_in[2];
    const float* ctx  = (const float*)d_in[3];
    const int*   mask = (const int*)d_in[4];
    const int*   index= (const int*)d_in[5];

    float* out  = (float*)d_out;                         /* B*IDX*E */
    float* attn = out + (size_t)B_ * IDX_ * E_;          /* B*N: scores then weights */

    int* counts    = (int*)d_ws;
    int* offsets   = counts  + B_ * IDX_;
    int* cursor    = offsets + B_ * IDX_;
    int* tokenlist = cursor  + B_ * IDX_;

    hipMemsetAsync(counts, 0, B_ * IDX_ * sizeof(int), stream);
    score_kernel  <<<2048, 256, 0, stream>>>(x, W, bias, ctx, mask, index, attn, counts);
    scan_kernel   <<<1, 1024, 0, stream>>>(counts, offsets, cursor);
    scatter_kernel<<<1024, 256, 0, stream>>>(index, cursor, tokenlist);
    attend_kernel <<<B_ * IDX_, 256, 0, stream>>>(x, counts, offsets, tokenlist, attn, out);
}